// Round 10
// baseline (381.396 us; speedup 1.0000x reference)
//
#include <hip/hip_runtime.h>
#include <hip/hip_bf16.h>

// GRN_GAT_Encoder round 10:
// r9 MISS: 8B/lane channel-split doubled request count -> agg1 89us, VALU up.
// r10 synthesis (best of r7/r8/r9): agg1 = 16B/lane full-channel gather (r8) +
// edge-partitioned logit pass w/ LDS (m,ss) merge (r9) + LDS weight precompute (r9) +
// edge-partitioned gather across 2 waves/node + LDS accumulator combine (r7 minus its
// duplicated logit pass). Serial chain 32->16 iters at full 1KB/instr. agg2 same.

#define NN    20000
#define EE    320000
#define E2    640000
#define FIN   256
#define FE    32
#define HIDD  128
#define NHEAD 4
#define HH    512   // NHEAD*HIDD
#define CAP   160   // max staged in-degree (mean 32, max ~70 for random graph)
#define AW    132   // padded LDS row stride (ushorts) for proj A tiles

typedef unsigned short ushort_t;
typedef short frag8 __attribute__((ext_vector_type(8)));
typedef float f32x4 __attribute__((ext_vector_type(4)));

__device__ inline ushort_t f2bf(float f){
  unsigned x = __float_as_uint(f);
  unsigned r = (x + 0x7fffu + ((x>>16)&1u)) >> 16;
  return (ushort_t)r;
}
__device__ inline float bf2f(ushort_t u){ return __uint_as_float(((unsigned)u)<<16); }
__device__ inline float lo_of(unsigned v){ return __uint_as_float(v<<16); }
__device__ inline float hi_of(unsigned v){ return __uint_as_float(v & 0xffff0000u); }

// ---------------- fused prep ----------------
__global__ void prep(const int* __restrict__ ei, int* __restrict__ cnt,
                     const float* __restrict__ x, ushort_t* __restrict__ xb,
                     const float* __restrict__ W1, ushort_t* __restrict__ W1t,
                     const float* __restrict__ W2, ushort_t* __restrict__ W2t,
                     const float* __restrict__ P1, ushort_t* __restrict__ P1th, ushort_t* __restrict__ P1tl,
                     const float* __restrict__ P2, ushort_t* __restrict__ P2th, ushort_t* __restrict__ P2tl,
                     const float* __restrict__ We1, const float* __restrict__ ae1,
                     const float* __restrict__ We2, const float* __restrict__ ae2,
                     float* __restrict__ v1, float* __restrict__ v2){
  int b = blockIdx.x, tid = threadIdx.x;
  if(b < 2500){
    int e = b*256 + tid;
    int dst = (e < EE) ? ei[EE + e] : ei[e - EE];
    atomicAdd(&cnt[dst], 1);
  } else if(b < 7500){
    int i = (b-2500)*256 + tid;
    float4 v = ((const float4*)x)[i];
    ushort4 o; o.x=f2bf(v.x); o.y=f2bf(v.y); o.z=f2bf(v.z); o.w=f2bf(v.w);
    ((ushort4*)xb)[i] = o;
  } else if(b < 8012){
    int idx = (b-7500)*256 + tid;               // FIN*HH
    int k = idx>>9, n = idx&511;
    W1t[n*FIN + k] = f2bf(W1[idx]);
  } else if(b < 8268){
    int idx = (b-8012)*256 + tid;               // HH*HIDD
    int k = idx>>7, n = idx&127;
    W2t[n*HH + k] = f2bf(W2[idx]);
  } else if(b < 8332){
    int idx = (b-8268)*256 + tid;               // HIDD*HIDD
    int k = idx>>7, n = idx&127;
    float v = P1[idx];
    ushort_t h = f2bf(v);
    P1th[n*HIDD + k] = h;
    P1tl[n*HIDD + k] = f2bf(v - bf2f(h));
  } else if(b < 8396){
    int idx = (b-8332)*256 + tid;
    int k = idx>>7, n = idx&127;
    float v = P2[idx];
    ushort_t h = f2bf(v);
    P2th[n*HIDD + k] = h;
    P2tl[n*HIDD + k] = f2bf(v - bf2f(h));
  } else {
    if(tid < FE*NHEAD){
      int f = tid>>2, h = tid&3;
      float s = 0.f;
      for(int c=0;c<HIDD;c++) s += We1[f*HH + h*HIDD + c] * ae1[h*HIDD + c];
      v1[f*4+h] = s;
    } else if(tid < FE*NHEAD + FE){
      int f = tid - FE*NHEAD;
      float s = 0.f;
      for(int c=0;c<HIDD;c++) s += We2[f*HIDD + c] * ae2[c];
      v2[f] = s;
    }
  }
}

// int4-vectorized scan
__global__ void scan_k(const int* __restrict__ cnt, int* __restrict__ rowptr){
  __shared__ int sums[1024];
  int tid = threadIdx.x;
  const int per = 20;   // 5 int4
  int base = tid*per;
  int v[20];
  if(base + per <= NN){
    #pragma unroll
    for(int q=0;q<5;q++) *(int4*)&v[q*4] = *(const int4*)&cnt[base + q*4];
  } else {
    for(int i=0;i<per;i++) v[i] = (base+i<NN)? cnt[base+i] : 0;
  }
  int s = 0;
  #pragma unroll
  for(int i=0;i<per;i++) s += v[i];
  sums[tid] = s; __syncthreads();
  for(int off=1; off<1024; off<<=1){
    int t = (tid>=off)? sums[tid-off] : 0;
    __syncthreads();
    sums[tid] += t;
    __syncthreads();
  }
  int run = (tid==0)? 0 : sums[tid-1];
  int rp[20];
  #pragma unroll
  for(int i=0;i<per;i++){ rp[i] = run; run += v[i]; }
  if(base + per <= NN){
    #pragma unroll
    for(int q=0;q<5;q++) *(int4*)&rowptr[base + q*4] = *(const int4*)&rp[q*4];
  } else {
    for(int i=0;i<per;i++) if(base+i<=NN) rowptr[base+i] = rp[i];
  }
  if(tid == 1000) rowptr[NN] = rp[0];   // base==20000==NN exactly; rp[0]==total
}

// ---------------- fused csr_fill | gemm1(+attn) ----------------
__global__ __launch_bounds__(256) void csr_gemm1(
    const int* __restrict__ ei, const float* __restrict__ ea,
    const float* __restrict__ v1, const float* __restrict__ v2,
    const int* __restrict__ rowptr, int* __restrict__ fcnt,
    int* __restrict__ csrc, float* __restrict__ cae1, float* __restrict__ cae2,
    const ushort_t* __restrict__ A, const ushort_t* __restrict__ Bt,
    ushort_t* __restrict__ C, int M,
    const float* __restrict__ as1, const float* __restrict__ ad1,
    float* __restrict__ s1n, float* __restrict__ d1n){
  __shared__ ushort_t As[128*32];
  __shared__ ushort_t Bs[128*32];
  __shared__ float sred[2][128], dred[2][128];
  __shared__ float sv1[FE*NHEAD];
  __shared__ float sv2[FE];
  int tid = threadIdx.x;
  int b = blockIdx.x;
  if(b < 1250){
    if(tid < FE*NHEAD) sv1[tid] = v1[tid];
    if(tid < FE)       sv2[tid] = v2[tid];
    __syncthreads();
    int e = b*256 + tid;
    int a = ei[e], bb = ei[EE+e];
    const float4* er4 = (const float4*)(ea + (long)e*FE);
    float a0=0,a1=0,a2=0,a3=0,ab=0;
    #pragma unroll
    for(int f4=0; f4<FE/4; f4++){
      float4 t = er4[f4];
      float tv[4] = {t.x, t.y, t.z, t.w};
      #pragma unroll
      for(int c=0;c<4;c++){
        int f = f4*4+c;
        float t1 = tv[c];
        a0 += t1*sv1[f*4+0]; a1 += t1*sv1[f*4+1]; a2 += t1*sv1[f*4+2]; a3 += t1*sv1[f*4+3];
        ab += t1*sv2[f];
      }
    }
    float4 c4; c4.x=a0; c4.y=a1; c4.z=a2; c4.w=a3;
    int pos = rowptr[bb] + atomicAdd(&fcnt[bb], 1);    // fwd
    csrc[pos] = a;
    *(float4*)(cae1 + (size_t)pos*4) = c4;
    cae2[pos] = ab;
    pos = rowptr[a] + atomicAdd(&fcnt[a], 1);          // rev
    csrc[pos] = bb;
    *(float4*)(cae1 + (size_t)pos*4) = c4;
    cae2[pos] = ab;
    return;
  }
  int g = b - 1250;
  int head = g & 3;
  int m0 = (g>>2)*128, n0 = head*128;
  int w = tid>>6, lane = tid&63;
  int qr = (w>>1)*64, qc = (w&1)*64;
  int lrow = lane&15, koff = (lane>>4)*8;
  f32x4 acc[4][4] = {};
  for(int k0=0; k0<FIN; k0+=32){
    #pragma unroll
    for(int rep=0;rep<2;rep++){
      int segid = tid + rep*256;
      int row = segid>>2, off = (segid&3)*8;
      int gr = m0 + row;
      int4 va = (gr<M) ? *(const int4*)(A + (long)gr*FIN + k0 + off) : int4{0,0,0,0};
      *(int4*)&As[row*32 + off] = va;
      int4 vb = *(const int4*)(Bt + (long)(n0+row)*FIN + k0 + off);
      *(int4*)&Bs[row*32 + off] = vb;
    }
    __syncthreads();
    frag8 af[4], bfr[4];
    #pragma unroll
    for(int i=0;i<4;i++) af[i]  = *(const frag8*)&As[(qr + i*16 + lrow)*32 + koff];
    #pragma unroll
    for(int j=0;j<4;j++) bfr[j] = *(const frag8*)&Bs[(qc + j*16 + lrow)*32 + koff];
    #pragma unroll
    for(int i=0;i<4;i++)
      #pragma unroll
      for(int j=0;j<4;j++)
        acc[i][j] = __builtin_amdgcn_mfma_f32_16x16x32_bf16(af[i], bfr[j], acc[i][j], 0,0,0);
    __syncthreads();
  }
  #pragma unroll
  for(int i=0;i<4;i++)
    #pragma unroll
    for(int j=0;j<4;j++)
      #pragma unroll
      for(int r=0;r<4;r++){
        int row = m0 + qr + i*16 + (lane>>4)*4 + r;
        int col = n0 + qc + j*16 + (lane&15);
        if(row<M) C[(long)row*HH + col] = f2bf(acc[i][j][r]);
      }
  float a_s[4], a_d[4];
  #pragma unroll
  for(int j=0;j<4;j++){
    a_s[j] = as1[head*HIDD + qc + j*16 + (lane&15)];
    a_d[j] = ad1[head*HIDD + qc + j*16 + (lane&15)];
  }
  #pragma unroll
  for(int i=0;i<4;i++)
    #pragma unroll
    for(int r=0;r<4;r++){
      float sp = acc[i][0][r]*a_s[0] + acc[i][1][r]*a_s[1] + acc[i][2][r]*a_s[2] + acc[i][3][r]*a_s[3];
      float dp = acc[i][0][r]*a_d[0] + acc[i][1][r]*a_d[1] + acc[i][2][r]*a_d[2] + acc[i][3][r]*a_d[3];
      #pragma unroll
      for(int o=1;o<=8;o<<=1){ sp += __shfl_xor(sp,o,64); dp += __shfl_xor(dp,o,64); }
      if((lane&15)==0){
        int rl = qr + i*16 + (lane>>4)*4 + r;
        sred[w&1][rl] = sp;
        dred[w&1][rl] = dp;
      }
    }
  __syncthreads();
  if(tid < 128){
    int gr = m0 + tid;
    if(gr < M){
      s1n[gr*4 + head] = sred[0][tid] + sred[1][tid];
      d1n[gr*4 + head] = dred[0][tid] + dred[1][tid];
    }
  }
}

// ---------------- gemm64 (+fused node_attn2) ----------------
__global__ __launch_bounds__(256) void gemm64_attn(const ushort_t* __restrict__ A, const ushort_t* __restrict__ Bt,
                                                   ushort_t* __restrict__ C, int M,
                                                   const float* __restrict__ as2, const float* __restrict__ ad2,
                                                   float* __restrict__ s2n, float* __restrict__ d2n){
  __shared__ ushort_t As[64*32];
  __shared__ ushort_t Bs[128*32];
  __shared__ float sred[4][64], dred[4][64];
  int tid = threadIdx.x;
  int m0 = blockIdx.y*64;
  int w = tid>>6, lane = tid&63;
  int qc = w*32;
  int lrow = lane&15, koff = (lane>>4)*8;
  f32x4 acc[4][2] = {};
  for(int k0=0; k0<HH; k0+=32){
    {
      int row = tid>>2, off = (tid&3)*8;
      int gr = m0 + row;
      int4 va = (gr<M) ? *(const int4*)(A + (long)gr*HH + k0 + off) : int4{0,0,0,0};
      *(int4*)&As[row*32 + off] = va;
    }
    #pragma unroll
    for(int rep=0;rep<2;rep++){
      int segid = tid + rep*256;
      int row = segid>>2, off = (segid&3)*8;
      int4 vb = *(const int4*)(Bt + (long)row*HH + k0 + off);
      *(int4*)&Bs[row*32 + off] = vb;
    }
    __syncthreads();
    frag8 af[4], bfr[2];
    #pragma unroll
    for(int i=0;i<4;i++) af[i]  = *(const frag8*)&As[(i*16 + lrow)*32 + koff];
    #pragma unroll
    for(int j=0;j<2;j++) bfr[j] = *(const frag8*)&Bs[(qc + j*16 + lrow)*32 + koff];
    #pragma unroll
    for(int i=0;i<4;i++)
      #pragma unroll
      for(int j=0;j<2;j++)
        acc[i][j] = __builtin_amdgcn_mfma_f32_16x16x32_bf16(af[i], bfr[j], acc[i][j], 0,0,0);
    __syncthreads();
  }
  #pragma unroll
  for(int i=0;i<4;i++)
    #pragma unroll
    for(int j=0;j<2;j++)
      #pragma unroll
      for(int r=0;r<4;r++){
        int row = m0 + i*16 + (lane>>4)*4 + r;
        int col = qc + j*16 + (lane&15);
        if(row<M) C[(long)row*HIDD + col] = f2bf(acc[i][j][r]);
      }
  float a_s[2], a_d[2];
  #pragma unroll
  for(int j=0;j<2;j++){
    a_s[j] = as2[qc + j*16 + (lane&15)];
    a_d[j] = ad2[qc + j*16 + (lane&15)];
  }
  #pragma unroll
  for(int i=0;i<4;i++)
    #pragma unroll
    for(int r=0;r<4;r++){
      float sp = acc[i][0][r]*a_s[0] + acc[i][1][r]*a_s[1];
      float dp = acc[i][0][r]*a_d[0] + acc[i][1][r]*a_d[1];
      #pragma unroll
      for(int o=1;o<=8;o<<=1){ sp += __shfl_xor(sp,o,64); dp += __shfl_xor(dp,o,64); }
      if((lane&15)==0){
        int rl = i*16 + (lane>>4)*4 + r;
        sred[w][rl] = sp;
        dred[w][rl] = dp;
      }
    }
  __syncthreads();
  if(tid < 64){
    int gr = m0 + tid;
    if(gr < M){
      s2n[gr] = sred[0][tid]+sred[1][tid]+sred[2][tid]+sred[3][tid];
      d2n[gr] = dred[0][tid]+dred[1][tid]+dred[2][tid]+dred[3][tid];
    }
  }
}

// ---------------- agg1: edge-split logit pass + edge-split 16B gather + LDS combine ----
__global__ __launch_bounds__(256) void agg1(const ushort_t* __restrict__ h1b, const int* __restrict__ rowptr,
                     const int* __restrict__ csrc,
                     const float* __restrict__ s1n, const float* __restrict__ d1n,
                     const float* __restrict__ cae1,
                     const float* __restrict__ b1, ushort_t* __restrict__ out1b){
  __shared__ float stw[2][CAP*4];     // logits -> normalized weights
  __shared__ int   sidx[2][CAP];
  __shared__ float pm[2][2][4], ps[2][2][4];
  __shared__ float part[2][8][64];    // wave-1 partial accumulators
  int tid = threadIdx.x;
  int nodeLoc = tid>>7;               // 2 nodes/block
  int wv = (tid>>6)&1;                // edge-half index
  int lane = tid&63;
  int n = blockIdx.x*2 + nodeLoc;
  int beg = rowptr[n], end = rowptr[n+1];
  int deg = end - beg;
  int h12 = lane&3;
  float dh = d1n[n*4 + h12];
  // logit pass over this wave's edge half (interleaved 16-blocks)
  float m = -1e30f, ss = 0.f;
  for(int base=beg + wv*16; base<end; base+=32){
    int e = base + (lane>>2);
    if(e<end){
      int s = csrc[e];
      float t = s1n[s*4 + h12] + dh + cae1[e*4 + h12];
      t = t>0.f? t : 0.2f*t;
      int j = e - beg;
      if(j < CAP){
        stw[nodeLoc][j*4 + h12] = t;
        if(h12==0) sidx[nodeLoc][j] = s;
      }
      float nm = fmaxf(m, t);
      ss = ss*__expf(m-nm) + __expf(t-nm);
      m = nm;
    }
  }
  #pragma unroll
  for(int o=4;o<=32;o<<=1){
    float mo = __shfl_xor(m, o, 64), so = __shfl_xor(ss, o, 64);
    float nm = fmaxf(m, mo);
    ss = ss*__expf(m-nm) + so*__expf(mo-nm);
    m = nm;
  }
  if(lane<4){ pm[nodeLoc][wv][lane] = m; ps[nodeLoc][wv][lane] = ss; }
  __syncthreads();
  float m4[4], i4[4];
  #pragma unroll
  for(int h=0;h<4;h++){
    float mA = pm[nodeLoc][0][h], mB = pm[nodeLoc][1][h];
    float sA = ps[nodeLoc][0][h], sB = ps[nodeLoc][1][h];
    float mf = fmaxf(mA, mB);
    float sf = sA*__expf(mA-mf) + sB*__expf(mB-mf);
    m4[h] = mf; i4[h] = sf>0.f ? 1.f/sf : 0.f;
  }
  int capn = deg < CAP ? deg : CAP;
  int tln = tid & 127;
  float mh = m4[h12], ih = i4[h12];   // tln&3 == h12
  for(int f=tln; f<capn*4; f+=128) stw[nodeLoc][f] = __expf(stw[nodeLoc][f]-mh)*ih;
  __syncthreads();
  // gather: contiguous edge halves per wave, full 512 channels at 16B/lane
  int hq = lane>>4;
  int half = (capn+1)>>1;
  int gb = wv*half;
  int ge = (gb+half < capn) ? gb+half : capn;
  float acc[8] = {};
  int j = gb;
  for(; j+3<ge; j+=4){
    int s0 = sidx[nodeLoc][j],   s1 = sidx[nodeLoc][j+1];
    int s2 = sidx[nodeLoc][j+2], s3 = sidx[nodeLoc][j+3];
    float w0 = stw[nodeLoc][(j  )*4 + hq];
    float w1 = stw[nodeLoc][(j+1)*4 + hq];
    float w2 = stw[nodeLoc][(j+2)*4 + hq];
    float w3 = stw[nodeLoc][(j+3)*4 + hq];
    uint4 v0 = *(const uint4*)(h1b + (long)s0*HH + lane*8);
    uint4 v1 = *(const uint4*)(h1b + (long)s1*HH + lane*8);
    uint4 v2 = *(const uint4*)(h1b + (long)s2*HH + lane*8);
    uint4 v3 = *(const uint4*)(h1b + (long)s3*HH + lane*8);
    acc[0] += w0*lo_of(v0.x) + w1*lo_of(v1.x) + w2*lo_of(v2.x) + w3*lo_of(v3.x);
    acc[1] += w0*hi_of(v0.x) + w1*hi_of(v1.x) + w2*hi_of(v2.x) + w3*hi_of(v3.x);
    acc[2] += w0*lo_of(v0.y) + w1*lo_of(v1.y) + w2*lo_of(v2.y) + w3*lo_of(v3.y);
    acc[3] += w0*hi_of(v0.y) + w1*hi_of(v1.y) + w2*hi_of(v2.y) + w3*hi_of(v3.y);
    acc[4] += w0*lo_of(v0.z) + w1*lo_of(v1.z) + w2*lo_of(v2.z) + w3*lo_of(v3.z);
    acc[5] += w0*hi_of(v0.z) + w1*hi_of(v1.z) + w2*hi_of(v2.z) + w3*hi_of(v3.z);
    acc[6] += w0*lo_of(v0.w) + w1*lo_of(v1.w) + w2*lo_of(v2.w) + w3*lo_of(v3.w);
    acc[7] += w0*hi_of(v0.w) + w1*hi_of(v1.w) + w2*hi_of(v2.w) + w3*hi_of(v3.w);
  }
  for(; j<ge; j++){
    int s0 = sidx[nodeLoc][j];
    float w0 = stw[nodeLoc][j*4 + hq];
    uint4 v0 = *(const uint4*)(h1b + (long)s0*HH + lane*8);
    acc[0] += w0*lo_of(v0.x); acc[1] += w0*hi_of(v0.x);
    acc[2] += w0*lo_of(v0.y); acc[3] += w0*hi_of(v0.y);
    acc[4] += w0*lo_of(v0.z); acc[5] += w0*hi_of(v0.z);
    acc[6] += w0*lo_of(v0.w); acc[7] += w0*hi_of(v0.w);
  }
  for(int jj=CAP+wv; jj<deg; jj+=2){   // overflow fallback, parity-split
    int e = beg + jj;
    int s0 = csrc[e];
    float t = s1n[s0*4 + hq] + d1n[n*4 + hq] + cae1[e*4 + hq];
    t = t>0.f? t : 0.2f*t;
    float w0 = __expf(t - m4[hq])*i4[hq];
    uint4 v0 = *(const uint4*)(h1b + (long)s0*HH + lane*8);
    acc[0] += w0*lo_of(v0.x); acc[1] += w0*hi_of(v0.x);
    acc[2] += w0*lo_of(v0.y); acc[3] += w0*hi_of(v0.y);
    acc[4] += w0*lo_of(v0.z); acc[5] += w0*hi_of(v0.z);
    acc[6] += w0*lo_of(v0.w); acc[7] += w0*hi_of(v0.w);
  }
  if(wv==1){
    #pragma unroll
    for(int c=0;c<8;c++) part[nodeLoc][c][lane] = acc[c];
  }
  __syncthreads();
  if(wv==0){
    #pragma unroll
    for(int c=0;c<8;c++) acc[c] += part[nodeLoc][c][lane];
    float4 bl = ((const float4*)b1)[lane*2];
    float4 bh = ((const float4*)b1)[lane*2+1];
    float bb[8] = {bl.x,bl.y,bl.z,bl.w,bh.x,bh.y,bh.z,bh.w};
    ushort_t o8[8];
    #pragma unroll
    for(int c=0;c<8;c++){
      float o = acc[c] + bb[c];
      o8[c] = f2bf(o>0.f? o : __expf(o)-1.f);   // ELU
    }
    uint4 pk;
    pk.x = (unsigned)o8[0] | ((unsigned)o8[1]<<16);
    pk.y = (unsigned)o8[2] | ((unsigned)o8[3]<<16);
    pk.z = (unsigned)o8[4] | ((unsigned)o8[5]<<16);
    pk.w = (unsigned)o8[6] | ((unsigned)o8[7]<<16);
    *(uint4*)(out1b + (long)n*HH + lane*8) = pk;
  }
}

// ---------------- agg2: edge-split logit pass + edge-split gather + LDS combine ----
__global__ __launch_bounds__(256) void agg2(const ushort_t* __restrict__ h2b, const int* __restrict__ rowptr,
                     const int* __restrict__ csrc,
                     const float* __restrict__ s2n, const float* __restrict__ d2n,
                     const float* __restrict__ cae2,
                     const float* __restrict__ b2, float* __restrict__ out2){
  __shared__ float stl[2][CAP];
  __shared__ int   sid[2][CAP];
  __shared__ float pm2[2][2], ps2[2][2];
  __shared__ float part2[2][2][64];
  int tid = threadIdx.x;
  int nodeLoc = tid>>7;
  int wv = (tid>>6)&1;
  int lane = tid&63;
  int n = blockIdx.x*2 + nodeLoc;
  int beg = rowptr[n], end = rowptr[n+1];
  int deg = end - beg;
  float dn = d2n[n];
  float m = -1e30f, ss = 0.f;
  for(int e=beg + wv*64 + lane; e<end; e+=128){
    int s = csrc[e];
    float t = s2n[s] + dn + cae2[e];
    t = t>0.f? t : 0.2f*t;
    int j = e - beg;
    if(j < CAP){ stl[nodeLoc][j] = t; sid[nodeLoc][j] = s; }
    float nm = fmaxf(m, t);
    ss = ss*__expf(m-nm) + __expf(t-nm);
    m = nm;
  }
  #pragma unroll
  for(int o=1;o<=32;o<<=1){
    float mo = __shfl_xor(m, o, 64), so = __shfl_xor(ss, o, 64);
    float nm = fmaxf(m, mo);
    ss = ss*__expf(m-nm) + so*__expf(mo-nm);
    m = nm;
  }
  if(lane==0){ pm2[nodeLoc][wv] = m; ps2[nodeLoc][wv] = ss; }
  __syncthreads();
  {
    float mA = pm2[nodeLoc][0], mB = pm2[nodeLoc][1];
    float sA = ps2[nodeLoc][0], sB = ps2[nodeLoc][1];
    m = fmaxf(mA, mB);
    ss = sA*__expf(mA-m) + sB*__expf(mB-m);
  }
  float inv = ss>0.f ? 1.f/ss : 0.f;
  int capn = deg < CAP ? deg : CAP;
  for(int j=tid&127; j<capn; j+=128) stl[nodeLoc][j] = __expf(stl[nodeLoc][j]-m)*inv;
  __syncthreads();
  int half = (capn+1)>>1;
  int gb = wv*half;
  int ge = (gb+half < capn) ? gb+half : capn;
  float a0=0.f, a1=0.f;
  int j = gb;
  for(; j+3<ge; j+=4){
    int s0 = sid[nodeLoc][j], s1 = sid[nodeLoc][j+1], s2 = sid[nodeLoc][j+2], s3 = sid[nodeLoc][j+3];
    float w0 = stl[nodeLoc][j], w1 = stl[nodeLoc][j+1], w2 = stl[nodeLoc][j+2], w3 = stl[nodeLoc][j+3];
    unsigned v0 = *(const unsigned*)(h2b + (long)s0*HIDD + 2*lane);
    unsigned v1 = *(const unsigned*)(h2b + (long)s1*HIDD + 2*lane);
    unsigned v2 = *(const unsigned*)(h2b + (long)s2*HIDD + 2*lane);
    unsigned v3 = *(const unsigned*)(h2b + (long)s3*HIDD + 2*lane);
    a0 += w0*lo_of(v0) + w1*lo_of(v1) + w2*lo_of(v2) + w3*lo_of(v3);
    a1 += w0*hi_of(v0) + w1*hi_of(v1) + w2*hi_of(v2) + w3*hi_of(v3);
  }
  for(; j<ge; j++){
    float w0 = stl[nodeLoc][j];
    unsigned v0 = *(const unsigned*)(h2b + (long)sid[nodeLoc][j]*HIDD + 2*lane);
    a0 += w0*lo_of(v0); a1 += w0*hi_of(v0);
  }
  for(int jj=CAP+wv; jj<deg; jj+=2){   // overflow fallback
    int e = beg + jj;
    int s0 = csrc[e];
    float t = s2n[s0] + dn + cae2[e];
    t = t>0.f? t : 0.2f*t;
    float w0 = __expf(t-m)*inv;
    unsigned v0 = *(const unsigned*)(h2b + (long)s0*HIDD + 2*lane);
    a0 += w0*lo_of(v0); a1 += w0*hi_of(v0);
  }
  if(wv==1){
    part2[nodeLoc][0][lane] = a0;
    part2[nodeLoc][1][lane] = a1;
  }
  __syncthreads();
  if(wv==0){
    a0 += part2[nodeLoc][0][lane];
    a1 += part2[nodeLoc][1][lane];
    float o0 = a0 + b2[2*lane];
    float o1 = a1 + b2[2*lane+1];
    float2 pk;
    pk.x = o0>0.f? o0 : __expf(o0)-1.f;
    pk.y = o1>0.f? o1 : __expf(o1)-1.f;
    *(float2*)(out2 + (long)n*HIDD + 2*lane) = pk;
  }
}

// ---------------- fused projection head ----------------
__global__ __launch_bounds__(256) void proj_fused(const float* __restrict__ A,
    const ushort_t* __restrict__ P1th, const ushort_t* __restrict__ P1tl,
    const ushort_t* __restrict__ P2th, const ushort_t* __restrict__ P2tl,
    const float* __restrict__ pb1, const float* __restrict__ pra,
    const float* __restrict__ pb2, float* __restrict__ OUT, int M,
    float* __restrict__ gbuf){
  __shared__ ushort_t Ah[64*AW], Al[64*AW];
  __shared__ ushort_t Bh[128*32], Bl[128*32];
  int tid = threadIdx.x;
  int m0 = blockIdx.x*64;
  int w = tid>>6, lane = tid&63;
  int qc = w*32;
  int lrow = lane&15, koff2 = (lane>>4)*8;
  f32x4 acc[4][2] = {};
  {
    int row = tid>>2, cb = (tid&3)*8;
    int gr = m0 + row;
    for(int c0=0;c0<HIDD;c0+=32){
      float4 u0{0,0,0,0}, u1{0,0,0,0};
      if(gr<M){
        u0 = *(const float4*)(A + (long)gr*HIDD + c0 + cb);
        u1 = *(const float4*)(A + (long)gr*HIDD + c0 + cb + 4);
      }
      float vv[8] = {u0.x,u0.y,u0.z,u0.w,u1.x,u1.y,u1.z,u1.w};
      unsigned ph[4], pl[4];
      #pragma unroll
      for(int c=0;c<4;c++){
        ushort_t h0 = f2bf(vv[2*c]),   l0 = f2bf(vv[2*c]   - bf2f(h0));
        ushort_t h1 = f2bf(vv[2*c+1]), l1 = f2bf(vv[2*c+1] - bf2f(h1));
        ph[c] = (unsigned)h0 | ((unsigned)h1<<16);
        pl[c] = (unsigned)l0 | ((unsigned)l1<<16);
      }
      *(uint4*)&Ah[row*AW + c0 + cb] = *(uint4*)ph;
      *(uint4*)&Al[row*AW + c0 + cb] = *(uint4*)pl;
    }
  }
  __syncthreads();
  for(int k0=0;k0<HIDD;k0+=32){
    #pragma unroll
    for(int rep=0;rep<2;rep++){
      int segid = tid + rep*256;
      int row = segid>>2, off = (segid&3)*8;
      *(int4*)&Bh[row*32 + off] = *(const int4*)(P1th + (long)row*HIDD + k0 + off);
      *(int4*)&Bl[row*32 + off] = *(const int4*)(P1tl + (long)row*HIDD + k0 + off);
    }
    __syncthreads();
    frag8 afh[4], afl[4], bfh[2], bfl[2];
    #pragma unroll
    for(int i=0;i<4;i++){
      afh[i] = *(const frag8*)&Ah[(i*16 + lrow)*AW + k0 + koff2];
      afl[i] = *(const frag8*)&Al[(i*16 + lrow)*AW + k0 + koff2];
    }
    #pragma unroll
    for(int j=0;j<2;j++){
      bfh[j] = *(const frag8*)&Bh[(qc + j*16 + lrow)*32 + koff2];
      bfl[j] = *(const frag8*)&Bl[(qc + j*16 + lrow)*32 + koff2];
    }
    #pragma unroll
    for(int i=0;i<4;i++)
      #pragma unroll
      for(int j=0;j<2;j++){
        acc[i][j] = __builtin_amdgcn_mfma_f32_16x16x32_bf16(afh[i], bfh[j], acc[i][j], 0,0,0);
        acc[i][j] = __builtin_amdgcn_mfma_f32_16x16x32_bf16(afh[i], bfl[j], acc[i][j], 0,0,0);
        acc[i][j] = __builtin_amdgcn_mfma_f32_16x16x32_bf16(afl[i], bfh[j], acc[i][j], 0,0,0);
      }
    __syncthreads();
  }
  float ap = pra[0];
  #pragma unroll
  for(int i=0;i<4;i++)
    #pragma unroll
    for(int j=0;j<2;j++)
      #pragma unroll
      for(int r=0;r<4;r++){
        int row = i*16 + (lane>>4)*4 + r;
        int col = qc + j*16 + (lane&15);
        float v = acc[i][j][r] + pb1[col];
        v = v>0.f? v : ap*v;
        ushort_t h = f2bf(v);
        Ah[row*AW + col] = h;
        Al[row*AW + col] = f2bf(v - bf2f(h));
        acc[i][j][r] = 0.f;
      }
  __syncthreads();
  for(int k0=0;k0<HIDD;k0+=32){
    #pragma unroll
    for(int rep=0;rep<2;rep++){
      int segid = tid + rep*256;
      int row = segid>>2, off = (segid&3)*8;
      *(int4*)&Bh[row*32 + off] = *(const int4*)(P2th + (long)row*HIDD + k0 + off);
      *(int4*)&Bl[row*32 + off] = *(const int4*)(P2tl + (long)row*HIDD + k0 + off);
    }
    __syncthreads();
    frag8 afh[4], afl[4], bfh[2], bfl[2];
    #pragma unroll
    for(int i=0;i<4;i++){
      afh[i] = *(const frag8*)&Ah[(i*16 + lrow)*AW + k0 + koff2];
      afl[i] = *(const frag8*)&Al[(i*16 + lrow)*AW + k0 + koff2];
    }
    #pragma unroll
    for(int j=0;j<2;j++){
      bfh[j] = *(const frag8*)&Bh[(qc + j*16 + lrow)*32 + koff2];
      bfl[j] = *(const frag8*)&Bl[(qc + j*16 + lrow)*32 + koff2];
    }
    #pragma unroll
    for(int i=0;i<4;i++)
      #pragma unroll
      for(int j=0;j<2;j++){
        acc[i][j] = __builtin_amdgcn_mfma_f32_16x16x32_bf16(afh[i], bfh[j], acc[i][j], 0,0,0);
        acc[i][j] = __builtin_amdgcn_mfma_f32_16x16x32_bf16(afh[i], bfl[j], acc[i][j], 0,0,0);
        acc[i][j] = __builtin_amdgcn_mfma_f32_16x16x32_bf16(afl[i], bfh[j], acc[i][j], 0,0,0);
      }
    __syncthreads();
  }
  float cs[2] = {0.f, 0.f};
  #pragma unroll
  for(int i=0;i<4;i++)
    #pragma unroll
    for(int j=0;j<2;j++)
      #pragma unroll
      for(int r=0;r<4;r++){
        int rowg = m0 + i*16 + (lane>>4)*4 + r;
        int col = qc + j*16 + (lane&15);
        if(rowg<M){
          float v = acc[i][j][r] + pb2[col];
          OUT[(long)rowg*HIDD + col] = v;
          cs[j] += v;
        }
      }
  #pragma unroll
  for(int j=0;j<2;j++){
    cs[j] += __shfl_xor(cs[j],16,64);
    cs[j] += __shfl_xor(cs[j],32,64);
    if((lane>>4)==0) atomicAdd(&gbuf[qc + j*16 + (lane&15)], cs[j]);
  }
}

__global__ void sigmoid_g(const float* __restrict__ gbuf, float* __restrict__ gout){
  int c = threadIdx.x;
  float m = gbuf[c] * (1.0f/NN);
  gout[c] = 1.f/(1.f+__expf(-m));
}

// ---------------- launch ----------------

extern "C" void kernel_launch(void* const* d_in, const int* in_sizes, int n_in,
                              void* d_out, int out_size, void* d_ws, size_t ws_size,
                              hipStream_t stream){
  const float* x    = (const float*)d_in[0];
  const int*   ei   = (const int*)  d_in[1];
  const float* ea   = (const float*)d_in[2];
  const float* W1   = (const float*)d_in[3];
  const float* We1  = (const float*)d_in[4];
  const float* as1  = (const float*)d_in[5];
  const float* ad1  = (const float*)d_in[6];
  const float* ae1  = (const float*)d_in[7];
  const float* b1   = (const float*)d_in[8];
  const float* W2   = (const float*)d_in[9];
  const float* We2  = (const float*)d_in[10];
  const float* as2  = (const float*)d_in[11];
  const float* ad2  = (const float*)d_in[12];
  const float* ae2  = (const float*)d_in[13];
  const float* b2   = (const float*)d_in[14];
  const float* P1   = (const float*)d_in[15];
  const float* pb1  = (const float*)d_in[16];
  const float* pra  = (const float*)d_in[17];
  const float* P2   = (const float*)d_in[18];
  const float* pb2  = (const float*)d_in[19];
  float* out = (float*)d_out;

  char* wsp = (char*)d_ws;
  size_t off = 0;
  auto alloc = [&](size_t bytes)->char*{
    char* p = wsp + off;
    off += (bytes + 255) & ~(size_t)255;
    return p;
  };
  ushort_t* h1b  = (ushort_t*)alloc(sizeof(ushort_t)*(size_t)NN*HH);
  ushort_t* out1b= (ushort_t*)alloc(sizeof(ushort_t)*(size_t)NN*HH);
  ushort_t* h2b  = (ushort_t*)alloc(sizeof(ushort_t)*(size_t)NN*HIDD);
  float*    out2 = (float*)  alloc(sizeof(float)*(size_t)NN*HIDD);
  ushort_t* xb   = (ushort_t*)alloc(sizeof(ushort_t)*(size_t)NN*FIN);
  ushort_t* W1t  = (ushort_t*)alloc(sizeof(ushort_t)*(size_t)HH*FIN);
  ushort_t* W2t  = (ushort_t*)alloc(sizeof(ushort_t)*(size_t)HIDD*HH);
  ushort_t* P1th = (ushort_t*)alloc(sizeof(ushort_t)*(size_t)HIDD*HIDD);
  ushort_t* P1tl = (ushort_t*)alloc(sizeof(ushort_t)*(size_t)HIDD*HIDD);
  ushort_t* P2th = (ushort_t*)alloc(sizeof(ushort_t)*(size_t)HIDD*HIDD);
  ushort_t* P2tl = (ushort_t*)alloc(sizeof(ushort_t)*(size_t)HIDD*HIDD);
  float* s1n   = (float*)alloc(sizeof(float)*NN*NHEAD);
  float* d1n   = (float*)alloc(sizeof(float)*NN*NHEAD);
  float* s2n   = (float*)alloc(sizeof(float)*NN);
  float* d2n   = (float*)alloc(sizeof(float)*NN);
  float* v1    = (float*)alloc(sizeof(float)*FE*NHEAD);
  float* v2    = (float*)alloc(sizeof(float)*FE);
  float* cae1  = (float*)alloc(sizeof(float)*(size_t)E2*NHEAD);
  float* cae2  = (float*)alloc(sizeof(float)*(size_t)E2);
  int*   rowptr= (int*)  alloc(sizeof(int)*(NN+1));
  int*   csrc  = (int*)  alloc(sizeof(int)*(size_t)E2);
  // zero-init trio: adjacent for one memset
  int*   cnt   = (int*)  alloc(sizeof(int)*NN);
  int*   fcnt  = (int*)  alloc(sizeof(int)*NN);
  float* gbuf  = (float*)alloc(sizeof(float)*HIDD);

  hipMemsetAsync(cnt, 0, 80128 + 80128 + 512, stream);

  prep     <<<8397, 256, 0, stream>>>(ei, cnt, x, xb, W1, W1t, W2, W2t,
                                      P1, P1th, P1tl, P2, P2th, P2tl,
                                      We1, ae1, We2, ae2, v1, v2);
  scan_k   <<<1, 1024, 0, stream>>>(cnt, rowptr);
  csr_gemm1<<<1250 + 628, 256, 0, stream>>>(ei, ea, v1, v2, rowptr, fcnt, csrc, cae1, cae2,
                                            xb, W1t, h1b, NN, as1, ad1, s1n, d1n);
  agg1     <<<NN/2, 256, 0, stream>>>(h1b, rowptr, csrc, s1n, d1n, cae1, b1, out1b);
  gemm64_attn<<<dim3(1, (NN+63)/64), 256, 0, stream>>>(out1b, W2t, h2b, NN, as2, ad2, s2n, d2n);
  agg2     <<<NN/2, 256, 0, stream>>>(h2b, rowptr, csrc, s2n, d2n, cae2, b2, out2);
  proj_fused<<<(NN+63)/64, 256, 0, stream>>>(out2, P1th, P1tl, P2th, P2tl,
                                             pb1, pra, pb2, out, NN, gbuf);
  sigmoid_g<<<1, 128, 0, stream>>>(gbuf, out + (size_t)NN*HIDD);
}